// Round 5
// baseline (352.955 us; speedup 1.0000x reference)
//
#include <hip/hip_runtime.h>
#include <hip/hip_bf16.h>
#include <stdint.h>

#define B_     16
#define T_     128
#define L_     100
#define IN_    100
#define EMB_   100
#define FEAT_  400
#define HID_   128
#define OUT_   50
#define RNNIN_ 500
#define VOCAB_ 10002
#define BT_    2048

// fp8 e4m3 HW-convert availability (gfx950). Fallback = bf16 tables (R4 path).
#if defined(__has_builtin)
#if __has_builtin(__builtin_amdgcn_cvt_pk_f32_fp8) && __has_builtin(__builtin_amdgcn_cvt_pk_fp8_f32)
#define HAVE_FP8 1
#endif
#endif
#ifndef HAVE_FP8
#define HAVE_FP8 0
#endif

typedef __attribute__((ext_vector_type(8))) short short8;
typedef __attribute__((ext_vector_type(4))) float f32x4;
typedef __attribute__((ext_vector_type(2))) float v2f;

__device__ __forceinline__ float lo2f(unsigned int u) {
    union { unsigned int i; float f; } v; v.i = u << 16; return v.f;
}
__device__ __forceinline__ float hi2f(unsigned int u) {
    union { unsigned int i; float f; } v; v.i = u & 0xffff0000u; return v.f;
}
__device__ __forceinline__ float fast_tanh(float x) {
    x = fminf(15.f, fmaxf(-15.f, x));
    float e = __expf(2.f * x);
    return (e - 1.f) * __builtin_amdgcn_rcpf(e + 1.f);
}
__device__ __forceinline__ float sigm(float x) {
    x = fminf(30.f, fmaxf(-30.f, x));
    float e = __expf(-x);
    return __builtin_amdgcn_rcpf(1.f + e);
}

// ---------- prep: bf16 casts (EN, EP, Whh) + Wih transpose ----------
__global__ void prep_k(const float* __restrict__ EN, const float* __restrict__ EP,
                       const float* __restrict__ Wih, const float* __restrict__ Whh,
                       __hip_bfloat16* __restrict__ ENb, __hip_bfloat16* __restrict__ EPb,
                       float* __restrict__ WihT, __hip_bfloat16* __restrict__ Whh_bf) {
    int t0 = blockIdx.x * 256 + threadIdx.x;
    int stride = gridDim.x * 256;
    int n1 = VOCAB_ * 100;
    for (int i = t0; i < n1; i += stride) ENb[i] = __float2bfloat16(EN[i]);
    for (int i = t0; i < n1; i += stride) EPb[i] = __float2bfloat16(EP[i]);
    for (int i = t0; i < 512 * 500; i += stride) {
        int r = i / 500, c = i - r * 500;
        WihT[(size_t)c * 512 + r] = Wih[i];
    }
    for (int i = t0; i < 512 * 128; i += stride) Whh_bf[i] = __float2bfloat16(Whh[i]);
}

// ---------- C[r][j] = sum_i A[r][i] * Wt[wrow+i][j], 32 rows/block ----------
// mode: 0 = f32 out, 1 = bf16 out, 2 = fp8 e4m3 out (if available)
__device__ __forceinline__ void table_gemm_body(
    const float* __restrict__ A, int lda, int rows,
    const float* __restrict__ Wt, int wrow,
    const float* __restrict__ bias, void* __restrict__ outp, int mode, int r0)
{
    __shared__ float As[32][100];
    int tid = threadIdx.x;
    for (int i = tid; i < 3200; i += 256) {
        int r = i / 100, c = i - r * 100;
        int gr = r0 + r;
        As[r][c] = (gr < rows) ? A[(size_t)gr * lda + c] : 0.f;
    }
    __syncthreads();
    int jj = tid & 63, rr = tid >> 6;
    float acc[8][7];
#pragma unroll
    for (int k = 0; k < 8; k++)
#pragma unroll
        for (int m = 0; m < 7; m++) acc[k][m] = 0.f;
    for (int i = 0; i < 100; i++) {
        float w[7];
#pragma unroll
        for (int m = 0; m < 7; m++) {
            int j = jj + (m << 6);
            w[m] = (j < 400) ? Wt[(size_t)(wrow + i) * 400 + j] : 0.f;
        }
#pragma unroll
        for (int k = 0; k < 8; k++) {
            float a = As[rr * 8 + k][i];
#pragma unroll
            for (int m = 0; m < 7; m++) acc[k][m] = fmaf(a, w[m], acc[k][m]);
        }
    }
#pragma unroll
    for (int k = 0; k < 8; k++) {
        int gr = r0 + rr * 8 + k;
        if (gr >= rows) continue;
#pragma unroll
        for (int m = 0; m < 7; m++) {
            int j = jj + (m << 6);
            if (j >= 400) continue;
            float v = acc[k][m];
            if (bias) v += bias[j];
#if HAVE_FP8
            if (mode == 2) {
                unsigned u = (unsigned)__builtin_amdgcn_cvt_pk_fp8_f32(v, v, 0, false);
                ((unsigned char*)outp)[(size_t)gr * 400 + j] = (unsigned char)(u & 0xff);
            } else
#endif
            if (mode == 1) ((__hip_bfloat16*)outp)[(size_t)gr * 400 + j] = __float2bfloat16(v);
            else           ((float*)outp)[(size_t)gr * 400 + j] = v;
        }
    }
}

#if HAVE_FP8
#define TBL_MODE 2
#else
#define TBL_MODE 1
#endif

__global__ __launch_bounds__(256) void table_gemm3(
    const float* __restrict__ EN, const float* __restrict__ EP,
    const float* __restrict__ Wt,
    void* __restrict__ Es, void* __restrict__ Ee, void* __restrict__ Epb)
{
    int which = blockIdx.y;
    const float* A = (which == 2) ? EP : EN;
    void* o = (which == 0) ? Es : ((which == 1) ? Ee : Epb);
    table_gemm_body(A, 100, VOCAB_, Wt, which * 100, nullptr, o, TBL_MODE, blockIdx.x * 32);
}

__global__ __launch_bounds__(256) void table_gemm_q(
    const float* __restrict__ x, const float* __restrict__ Wt,
    const float* __restrict__ bias, float* __restrict__ q)
{
    table_gemm_body(x, 400, BT_, Wt, 300, bias, (void*)q, 0, blockIdx.x * 32);
}

// ---------- stage A: ctx[bt][l] = sum_j tanh(Es+Ee+Ep+q)*Wa ----------
__global__ __launch_bounds__(256) void stage_a(
    const float* __restrict__ x,
    const void* __restrict__ Esv, const void* __restrict__ Eev,
    const void* __restrict__ Epv,
    const float* __restrict__ q, const float* __restrict__ Wa,
    float* __restrict__ ctx)
{
    __shared__ int idx_s[300];
    int bt = blockIdx.x, tid = threadIdx.x;
    const float* xr = x + (size_t)bt * 400 + 100;
    for (int i = tid; i < 300; i += 256) idx_s[i] = (int)xr[i];
    int lane = tid & 63, wave = tid >> 6;
    bool act = lane < 50;
    int j0 = lane * 8;
    float qv[8], wv[8];
    if (act) {
        float4 qa = *(const float4*)(q + (size_t)bt * 400 + j0);
        float4 qb = *(const float4*)(q + (size_t)bt * 400 + j0 + 4);
        float4 wa = *(const float4*)(Wa + j0);
        float4 wb = *(const float4*)(Wa + j0 + 4);
        qv[0]=qa.x; qv[1]=qa.y; qv[2]=qa.z; qv[3]=qa.w;
        qv[4]=qb.x; qv[5]=qb.y; qv[6]=qb.z; qv[7]=qb.w;
        wv[0]=wa.x; wv[1]=wa.y; wv[2]=wa.z; wv[3]=wa.w;
        wv[4]=wb.x; wv[5]=wb.y; wv[6]=wb.z; wv[7]=wb.w;
    } else {
#pragma unroll
        for (int jj = 0; jj < 8; jj++) { qv[jj] = 0.f; wv[jj] = 0.f; }
    }
    __syncthreads();
    for (int l = wave; l < 100; l += 4) {
        int i0 = idx_s[3 * l], i1 = idx_s[3 * l + 1], i2 = idx_s[3 * l + 2];
        float sum = 0.f;
        if (act) {
            float zs[8];
#if HAVE_FP8
            const unsigned char* Es8 = (const unsigned char*)Esv;
            const unsigned char* Ee8 = (const unsigned char*)Eev;
            const unsigned char* Ep8 = (const unsigned char*)Epv;
            uint2 a  = ((const uint2*)(Es8 + (size_t)i0 * 400))[lane];
            uint2 b  = ((const uint2*)(Ee8 + (size_t)i2 * 400))[lane];
            uint2 cc = ((const uint2*)(Ep8 + (size_t)i1 * 400))[lane];
            v2f s01 = __builtin_amdgcn_cvt_pk_f32_fp8((int)a.x, false);
            v2f s23 = __builtin_amdgcn_cvt_pk_f32_fp8((int)a.x, true);
            v2f s45 = __builtin_amdgcn_cvt_pk_f32_fp8((int)a.y, false);
            v2f s67 = __builtin_amdgcn_cvt_pk_f32_fp8((int)a.y, true);
            v2f e01 = __builtin_amdgcn_cvt_pk_f32_fp8((int)b.x, false);
            v2f e23 = __builtin_amdgcn_cvt_pk_f32_fp8((int)b.x, true);
            v2f e45 = __builtin_amdgcn_cvt_pk_f32_fp8((int)b.y, false);
            v2f e67 = __builtin_amdgcn_cvt_pk_f32_fp8((int)b.y, true);
            v2f p01 = __builtin_amdgcn_cvt_pk_f32_fp8((int)cc.x, false);
            v2f p23 = __builtin_amdgcn_cvt_pk_f32_fp8((int)cc.x, true);
            v2f p45 = __builtin_amdgcn_cvt_pk_f32_fp8((int)cc.y, false);
            v2f p67 = __builtin_amdgcn_cvt_pk_f32_fp8((int)cc.y, true);
            zs[0] = s01.x + e01.x + p01.x + qv[0];
            zs[1] = s01.y + e01.y + p01.y + qv[1];
            zs[2] = s23.x + e23.x + p23.x + qv[2];
            zs[3] = s23.y + e23.y + p23.y + qv[3];
            zs[4] = s45.x + e45.x + p45.x + qv[4];
            zs[5] = s45.y + e45.y + p45.y + qv[5];
            zs[6] = s67.x + e67.x + p67.x + qv[6];
            zs[7] = s67.y + e67.y + p67.y + qv[7];
#else
            const __hip_bfloat16* Es = (const __hip_bfloat16*)Esv;
            const __hip_bfloat16* Ee = (const __hip_bfloat16*)Eev;
            const __hip_bfloat16* Ep = (const __hip_bfloat16*)Epv;
            uint4 a  = *((const uint4*)(Es + (size_t)i0 * 400) + lane);
            uint4 b  = *((const uint4*)(Ee + (size_t)i2 * 400) + lane);
            uint4 cc = *((const uint4*)(Ep + (size_t)i1 * 400) + lane);
            zs[0] = lo2f(a.x)+lo2f(b.x)+lo2f(cc.x)+qv[0];
            zs[1] = hi2f(a.x)+hi2f(b.x)+hi2f(cc.x)+qv[1];
            zs[2] = lo2f(a.y)+lo2f(b.y)+lo2f(cc.y)+qv[2];
            zs[3] = hi2f(a.y)+hi2f(b.y)+hi2f(cc.y)+qv[3];
            zs[4] = lo2f(a.z)+lo2f(b.z)+lo2f(cc.z)+qv[4];
            zs[5] = hi2f(a.z)+hi2f(b.z)+hi2f(cc.z)+qv[5];
            zs[6] = lo2f(a.w)+lo2f(b.w)+lo2f(cc.w)+qv[6];
            zs[7] = hi2f(a.w)+hi2f(b.w)+hi2f(cc.w)+qv[7];
#endif
#pragma unroll
            for (int jj = 0; jj < 8; jj++) sum = fmaf(fast_tanh(zs[jj]), wv[jj], sum);
        }
#pragma unroll
        for (int off = 32; off; off >>= 1) sum += __shfl_xor(sum, off);
        if (lane == 0) ctx[(size_t)bt * 100 + l] = sum;
    }
}

// ---------- softmax over T: one wave per (b,l) ----------
__global__ __launch_bounds__(256) void softmax_w(
    const float* __restrict__ ctx, float* __restrict__ attn)
{
    int wid = blockIdx.x * 4 + (threadIdx.x >> 6);   // 0..1599
    int lane = threadIdx.x & 63;
    int b = wid / 100, l = wid - b * 100;
    size_t base = (size_t)b * 128 * 100 + l;
    float v0 = ctx[base + (size_t)lane * 100];
    float v1 = ctx[base + (size_t)(lane + 64) * 100];
    float m = fmaxf(v0, v1);
#pragma unroll
    for (int off = 32; off; off >>= 1) m = fmaxf(m, __shfl_xor(m, off));
    float e0 = __expf(v0 - m), e1 = __expf(v1 - m);
    float s = e0 + e1;
#pragma unroll
    for (int off = 32; off; off >>= 1) s += __shfl_xor(s, off);
    float rs = 1.f / s;
    attn[base + (size_t)lane * 100] = e0 * rs;
    attn[base + (size_t)(lane + 64) * 100] = e1 * rs;
}

// ---------- stage C: weighted re-gather of raw embeddings (bf16) ----------
__global__ __launch_bounds__(128) void stage_c(
    const float* __restrict__ x, const float* __restrict__ attn,
    const unsigned short* __restrict__ ENb, const unsigned short* __restrict__ EPb,
    float* __restrict__ cv)
{
    __shared__ float at[100];
    __shared__ int idx[300];
    int bt = blockIdx.x, tid = threadIdx.x;
    if (tid < 100) at[tid] = attn[(size_t)bt * 100 + tid];
    const float* xr = x + (size_t)bt * 400 + 100;
    for (int i = tid; i < 300; i += 128) idx[i] = (int)xr[i];
    __syncthreads();
    int d = tid;
    if (d < 100) {
        float as = 0.f, ae = 0.f, ap = 0.f, sa = 0.f;
#pragma unroll 4
        for (int l = 0; l < 100; l++) {
            float a = at[l]; sa += a;
            as = fmaf(a, lo2f(ENb[(size_t)idx[3 * l] * 100 + d]), as);
            ae = fmaf(a, lo2f(ENb[(size_t)idx[3 * l + 2] * 100 + d]), ae);
            ap = fmaf(a, lo2f(EPb[(size_t)idx[3 * l + 1] * 100 + d]), ap);
        }
        float* o = cv + (size_t)bt * 400;
        o[d] = as; o[100 + d] = ae; o[200 + d] = ap;
        o[300 + d] = x[(size_t)bt * 400 + d] * sa;
    }
}

// ---------- X = rnn_in @ Wih.T + biases ----------
__global__ __launch_bounds__(512) void gemm_x(
    const float* __restrict__ x, const float* __restrict__ cv,
    const float* __restrict__ WihT, const float* __restrict__ bih,
    const float* __restrict__ bhh, float* __restrict__ X)
{
    __shared__ float ins[8][500];
    int r0 = blockIdx.x * 8, tid = threadIdx.x;
    for (int i = tid; i < 4000; i += 512) {
        int r = i / 500, k = i - r * 500;
        ins[r][k] = (k < 100) ? x[(size_t)(r0 + r) * 400 + k]
                              : cv[(size_t)(r0 + r) * 400 + (k - 100)];
    }
    __syncthreads();
    int g = tid;
    float acc[8];
#pragma unroll
    for (int r = 0; r < 8; r++) acc[r] = 0.f;
    for (int k4 = 0; k4 < 125; k4++) {
        int k = k4 * 4;
        float w0 = WihT[(size_t)k * 512 + g];
        float w1 = WihT[(size_t)(k + 1) * 512 + g];
        float w2 = WihT[(size_t)(k + 2) * 512 + g];
        float w3 = WihT[(size_t)(k + 3) * 512 + g];
#pragma unroll
        for (int r = 0; r < 8; r++) {
            float4 a = *(const float4*)&ins[r][k];
            acc[r] = fmaf(a.x, w0, fmaf(a.y, w1, fmaf(a.z, w2, fmaf(a.w, w3, acc[r]))));
        }
    }
    float bias = bih[g] + bhh[g];
#pragma unroll
    for (int r = 0; r < 8; r++) X[(size_t)(r0 + r) * 512 + g] = acc[r] + bias;
}

// ---------- LSTM via MFMA, chunked LDS staging, fused FC epilogue ----------
// 8 waves; wave w owns hidden units j in [w*16, w*16+16).
// Tile n (gate) at cols [n*128 + w*16, +16). Split accumulators: 2 chains of 2.
// Per chunk of 16 steps: refill Xs (global, drained once), 16 barrier-steps
// (LDS-only), then fused FC: out[b][t][o] = sigm(h . Wfc[:,o] + bfc[o]).
__global__ __launch_bounds__(512, 1) void lstm_k(
    const float* __restrict__ X, const __hip_bfloat16* __restrict__ Whh_bf,
    const float* __restrict__ Wfc, const float* __restrict__ bfc,
    float* __restrict__ out)
{
    int b = blockIdx.x, tid = threadIdx.x;
    int wave = tid >> 6, lane = tid & 63;
    int col = lane & 15, kg = lane >> 4;

    short8 bf[4][4];
#pragma unroll
    for (int n = 0; n < 4; n++) {
        int g = n * 128 + wave * 16 + col;
#pragma unroll
        for (int kk = 0; kk < 4; kk++)
            bf[n][kk] = *(const short8*)(Whh_bf + (size_t)g * 128 + kk * 32 + kg * 8);
    }

    __shared__ __hip_bfloat16 h_bf[128];
    __shared__ float Xs[16][512];     // 32 KB: current 16-step X chunk
    __shared__ float hsb_s[16][128];  // 8 KB: h outputs for this chunk
    __shared__ float Wfc_s[128 * 50]; // 25.6 KB
    __shared__ float bfc_s[50];
    float c = 0.f;
    if (tid < 128) h_bf[tid] = __float2bfloat16(0.f);
    for (int i = tid; i < 6400; i += 512) Wfc_s[i] = Wfc[i];
    if (tid < 50) bfc_s[tid] = bfc[tid];
    const float* xb = X + (size_t)b * 128 * 512;
    int j = wave * 16 + col;

    __syncthreads();

    for (int tc = 0; tc < 8; tc++) {
        // ---- refill Xs with steps tc*16 .. tc*16+15 (coalesced, once/chunk) ----
        {
            const float* src = xb + (size_t)tc * 16 * 512 + tid;
#pragma unroll
            for (int k = 0; k < 16; k++) Xs[k][tid] = src[k * 512];
        }
        __syncthreads();   // drains refill loads (and prior chunk's out stores)

#pragma unroll 1
        for (int ts = 0; ts < 16; ts++) {
            // early X-addend reads (independent of h -> latency hidden under MFMA)
            float xi = Xs[ts][j], xf = Xs[ts][128 + j];
            float xg = Xs[ts][256 + j], xo = Xs[ts][384 + j];

            short8 af[4];
            short8 zz = {};
#pragma unroll
            for (int kk = 0; kk < 4; kk++) {
                af[kk] = zz;
                if (col == 0) af[kk] = *(const short8*)(h_bf + kk * 32 + kg * 8);
            }
            f32x4 a0[4], a1[4];
#pragma unroll
            for (int n = 0; n < 4; n++) { a0[n] = (f32x4){0,0,0,0}; a1[n] = (f32x4){0,0,0,0}; }
            // two independent 2-deep chains per gate
#pragma unroll
            for (int n = 0; n < 4; n++) a0[n] = __builtin_amdgcn_mfma_f32_16x16x32_bf16(af[0], bf[n][0], a0[n], 0, 0, 0);
#pragma unroll
            for (int n = 0; n < 4; n++) a1[n] = __builtin_amdgcn_mfma_f32_16x16x32_bf16(af[2], bf[n][2], a1[n], 0, 0, 0);
#pragma unroll
            for (int n = 0; n < 4; n++) a0[n] = __builtin_amdgcn_mfma_f32_16x16x32_bf16(af[1], bf[n][1], a0[n], 0, 0, 0);
#pragma unroll
            for (int n = 0; n < 4; n++) a1[n] = __builtin_amdgcn_mfma_f32_16x16x32_bf16(af[3], bf[n][3], a1[n], 0, 0, 0);

            if (lane < 16) {
                float pi = a0[0][0] + a1[0][0] + xi;
                float pf = a0[1][0] + a1[1][0] + xf;
                float pg = a0[2][0] + a1[2][0] + xg;
                float po = a0[3][0] + a1[3][0] + xo;
                c = sigm(pf) * c + sigm(pi) * fast_tanh(pg);
                float hn = sigm(po) * fast_tanh(c);
                h_bf[j] = __float2bfloat16(hn);
                hsb_s[ts][j] = hn;
            }
            __syncthreads();   // LDS-only outstanding -> near-free
        }

        // ---- fused FC for this chunk: out[b][tc*16+ts][o] ----
        for (int i = tid; i < 800; i += 512) {
            int ts = i / 50, o = i - ts * 50;
            float a = bfc_s[o];
            const float* hrow = hsb_s[ts];
#pragma unroll 4
            for (int k = 0; k < 128; k++) a = fmaf(hrow[k], Wfc_s[k * 50 + o], a);
            out[((size_t)b * 128 + tc * 16 + ts) * 50 + o] = sigm(a);
        }
        // out stores are fire-and-forget; drained at next refill's barrier.
    }
}

extern "C" void kernel_launch(void* const* d_in, const int* in_sizes, int n_in,
                              void* d_out, int out_size, void* d_ws, size_t ws_size,
                              hipStream_t stream) {
    const float* x   = (const float*)d_in[0];
    const float* EN  = (const float*)d_in[1];
    const float* EP  = (const float*)d_in[2];
    const float* Wt  = (const float*)d_in[3];
    const float* bt  = (const float*)d_in[4];
    const float* Wa  = (const float*)d_in[5];
    // d_in[6] = b_a: uniform shift along the softmax axis -> cancels, unused.
    const float* Wih = (const float*)d_in[7];
    const float* Whh = (const float*)d_in[8];
    const float* bih = (const float*)d_in[9];
    const float* bhh = (const float*)d_in[10];
    const float* Wfc = (const float*)d_in[11];
    const float* bfc = (const float*)d_in[12];
    float* out = (float*)d_out;

    char* ws = (char*)d_ws;
    size_t off = 0;
    auto alloc = [&](size_t bytes) -> char* {
        char* p = ws + off;
        off = (off + bytes + 255) & ~(size_t)255;
        return p;
    };
    // Sized for bf16 worst case; fp8 mode uses half of each (host cannot
    // reliably see the device-side HAVE_FP8, so allocate the max).
    void* Es  = (void*)alloc((size_t)VOCAB_ * 400 * 2);
    void* Ee  = (void*)alloc((size_t)VOCAB_ * 400 * 2);
    void* Epb = (void*)alloc((size_t)VOCAB_ * 400 * 2);
    __hip_bfloat16* ENb = (__hip_bfloat16*)alloc((size_t)VOCAB_ * 100 * 2);
    __hip_bfloat16* EPb = (__hip_bfloat16*)alloc((size_t)VOCAB_ * 100 * 2);
    float* q    = (float*)alloc((size_t)BT_ * 400 * 4);
    float* ctx  = (float*)alloc((size_t)BT_ * 100 * 4);
    float* attn = (float*)alloc((size_t)BT_ * 100 * 4);
    float* cv   = (float*)alloc((size_t)BT_ * 400 * 4);
    float* X    = (float*)alloc((size_t)BT_ * 512 * 4);
    float* WihT = (float*)alloc((size_t)500 * 512 * 4);
    __hip_bfloat16* Whh_bf = (__hip_bfloat16*)alloc((size_t)512 * 128 * 2);

    prep_k<<<1024, 256, 0, stream>>>(EN, EP, Wih, Whh, ENb, EPb, WihT, Whh_bf);
    int egrid = (VOCAB_ + 31) / 32;   // 313
    table_gemm3<<<dim3(egrid, 3), 256, 0, stream>>>(EN, EP, Wt, Es, Ee, Epb);
    table_gemm_q<<<BT_ / 32, 256, 0, stream>>>(x, Wt, bt, q);

    stage_a<<<BT_, 256, 0, stream>>>(x, Es, Ee, Epb, q, Wa, ctx);
    softmax_w<<<400, 256, 0, stream>>>(ctx, attn);
    stage_c<<<BT_, 128, 0, stream>>>(x, attn, (const unsigned short*)ENb,
                                     (const unsigned short*)EPb, cv);
    gemm_x<<<BT_ / 8, 512, 0, stream>>>(x, cv, WihT, bih, bhh, X);
    lstm_k<<<B_, 512, 0, stream>>>(X, Whh_bf, Wfc, bfc, out);
}

// Round 6
// 310.903 us; speedup vs baseline: 1.1353x; 1.1353x over previous
//
#include <hip/hip_runtime.h>
#include <hip/hip_bf16.h>
#include <stdint.h>

#define B_     16
#define T_     128
#define L_     100
#define IN_    100
#define EMB_   100
#define FEAT_  400
#define HID_   128
#define OUT_   50
#define RNNIN_ 500
#define VOCAB_ 10002
#define BT_    2048

// fp8 e4m3 HW-convert availability (gfx950). Fallback = bf16 tables.
#if defined(__has_builtin)
#if __has_builtin(__builtin_amdgcn_cvt_pk_f32_fp8) && __has_builtin(__builtin_amdgcn_cvt_pk_fp8_f32)
#define HAVE_FP8 1
#endif
#endif
#ifndef HAVE_FP8
#define HAVE_FP8 0
#endif

typedef __attribute__((ext_vector_type(8))) short short8;
typedef __attribute__((ext_vector_type(4))) float f32x4;
typedef __attribute__((ext_vector_type(2))) float v2f;

__device__ __forceinline__ float lo2f(unsigned int u) {
    union { unsigned int i; float f; } v; v.i = u << 16; return v.f;
}
__device__ __forceinline__ float hi2f(unsigned int u) {
    union { unsigned int i; float f; } v; v.i = u & 0xffff0000u; return v.f;
}
__device__ __forceinline__ float fast_tanh(float x) {
    x = fminf(15.f, fmaxf(-15.f, x));
    float e = __expf(2.f * x);
    return (e - 1.f) * __builtin_amdgcn_rcpf(e + 1.f);
}
__device__ __forceinline__ float sigm(float x) {
    x = fminf(30.f, fmaxf(-30.f, x));
    float e = __expf(-x);
    return __builtin_amdgcn_rcpf(1.f + e);
}

// ---------- C[r][j] = sum_i A[r][i] * Wt[wrow+i][j], 32 rows/block ----------
// mode: 0 = f32 out, 1 = bf16 out, 2 = fp8 e4m3 out (if available)
__device__ __forceinline__ void table_gemm_body(
    const float* __restrict__ A, int lda, int rows,
    const float* __restrict__ Wt, int wrow,
    const float* __restrict__ bias, void* __restrict__ outp, int mode, int r0)
{
    __shared__ float As[32][100];
    int tid = threadIdx.x;
    for (int i = tid; i < 3200; i += 256) {
        int r = i / 100, c = i - r * 100;
        int gr = r0 + r;
        As[r][c] = (gr < rows) ? A[(size_t)gr * lda + c] : 0.f;
    }
    __syncthreads();
    int jj = tid & 63, rr = tid >> 6;
    float acc[8][7];
#pragma unroll
    for (int k = 0; k < 8; k++)
#pragma unroll
        for (int m = 0; m < 7; m++) acc[k][m] = 0.f;
    for (int i = 0; i < 100; i++) {
        float w[7];
#pragma unroll
        for (int m = 0; m < 7; m++) {
            int j = jj + (m << 6);
            w[m] = (j < 400) ? Wt[(size_t)(wrow + i) * 400 + j] : 0.f;
        }
#pragma unroll
        for (int k = 0; k < 8; k++) {
            float a = As[rr * 8 + k][i];
#pragma unroll
            for (int m = 0; m < 7; m++) acc[k][m] = fmaf(a, w[m], acc[k][m]);
        }
    }
#pragma unroll
    for (int k = 0; k < 8; k++) {
        int gr = r0 + rr * 8 + k;
        if (gr >= rows) continue;
#pragma unroll
        for (int m = 0; m < 7; m++) {
            int j = jj + (m << 6);
            if (j >= 400) continue;
            float v = acc[k][m];
            if (bias) v += bias[j];
#if HAVE_FP8
            if (mode == 2) {
                unsigned u = (unsigned)__builtin_amdgcn_cvt_pk_fp8_f32(v, v, 0, false);
                ((unsigned char*)outp)[(size_t)gr * 400 + j] = (unsigned char)(u & 0xff);
            } else
#endif
            if (mode == 1) ((__hip_bfloat16*)outp)[(size_t)gr * 400 + j] = __float2bfloat16(v);
            else           ((float*)outp)[(size_t)gr * 400 + j] = v;
        }
    }
}

#if HAVE_FP8
#define TBL_MODE 2
#else
#define TBL_MODE 1
#endif

#define EGRID 313   // ceil(VOCAB_/32)

// ---------- merged setup: table_gemm_q | table_gemm3 | prep casts ----------
// blocks [0,64): q-GEMM; [64, 64+3*313): the three table GEMMs;
// [1003, 1003+256): bf16 casts (EN,EP,Whh) + Wih transpose via grid-stride.
__global__ __launch_bounds__(256) void setup_k(
    const float* __restrict__ x, const float* __restrict__ EN,
    const float* __restrict__ EP, const float* __restrict__ Wt,
    const float* __restrict__ bt, const float* __restrict__ Wih,
    const float* __restrict__ Whh,
    float* __restrict__ q,
    void* __restrict__ Es, void* __restrict__ Ee, void* __restrict__ Epb,
    __hip_bfloat16* __restrict__ ENb, __hip_bfloat16* __restrict__ EPb,
    float* __restrict__ WihT, __hip_bfloat16* __restrict__ Whh_bf)
{
    int blk = blockIdx.x;
    if (blk < 64) {
        table_gemm_body(x, 400, BT_, Wt, 300, bt, (void*)q, 0, blk * 32);
    } else if (blk < 64 + 3 * EGRID) {
        int t = blk - 64;
        int which = t / EGRID, r0 = (t - which * EGRID) * 32;
        const float* A = (which == 2) ? EP : EN;
        void* o = (which == 0) ? Es : ((which == 1) ? Ee : Epb);
        table_gemm_body(A, 100, VOCAB_, Wt, which * 100, nullptr, o, TBL_MODE, r0);
    } else {
        int t0 = (blk - (64 + 3 * EGRID)) * 256 + threadIdx.x;
        const int stride = 256 * 256;
        int n1 = VOCAB_ * 100;
        for (int i = t0; i < n1; i += stride) ENb[i] = __float2bfloat16(EN[i]);
        for (int i = t0; i < n1; i += stride) EPb[i] = __float2bfloat16(EP[i]);
        for (int i = t0; i < 512 * 500; i += stride) {
            int r = i / 500, c = i - r * 500;
            WihT[(size_t)c * 512 + r] = Wih[i];
        }
        for (int i = t0; i < 512 * 128; i += stride) Whh_bf[i] = __float2bfloat16(Whh[i]);
    }
}

// ---------- stage A: ctx[bt][l] = sum_j tanh(Es+Ee+Ep+q)*Wa ----------
__global__ __launch_bounds__(256) void stage_a(
    const float* __restrict__ x,
    const void* __restrict__ Esv, const void* __restrict__ Eev,
    const void* __restrict__ Epv,
    const float* __restrict__ q, const float* __restrict__ Wa,
    float* __restrict__ ctx)
{
    __shared__ int idx_s[300];
    int bt = blockIdx.x, tid = threadIdx.x;
    const float* xr = x + (size_t)bt * 400 + 100;
    for (int i = tid; i < 300; i += 256) idx_s[i] = (int)xr[i];
    int lane = tid & 63, wave = tid >> 6;
    bool act = lane < 50;
    int j0 = lane * 8;
    float qv[8], wv[8];
    if (act) {
        float4 qa = *(const float4*)(q + (size_t)bt * 400 + j0);
        float4 qb = *(const float4*)(q + (size_t)bt * 400 + j0 + 4);
        float4 wa = *(const float4*)(Wa + j0);
        float4 wb = *(const float4*)(Wa + j0 + 4);
        qv[0]=qa.x; qv[1]=qa.y; qv[2]=qa.z; qv[3]=qa.w;
        qv[4]=qb.x; qv[5]=qb.y; qv[6]=qb.z; qv[7]=qb.w;
        wv[0]=wa.x; wv[1]=wa.y; wv[2]=wa.z; wv[3]=wa.w;
        wv[4]=wb.x; wv[5]=wb.y; wv[6]=wb.z; wv[7]=wb.w;
    } else {
#pragma unroll
        for (int jj = 0; jj < 8; jj++) { qv[jj] = 0.f; wv[jj] = 0.f; }
    }
    __syncthreads();
    for (int l = wave; l < 100; l += 4) {
        int i0 = idx_s[3 * l], i1 = idx_s[3 * l + 1], i2 = idx_s[3 * l + 2];
        float sum = 0.f;
        if (act) {
            float zs[8];
#if HAVE_FP8
            const unsigned char* Es8 = (const unsigned char*)Esv;
            const unsigned char* Ee8 = (const unsigned char*)Eev;
            const unsigned char* Ep8 = (const unsigned char*)Epv;
            uint2 a  = ((const uint2*)(Es8 + (size_t)i0 * 400))[lane];
            uint2 b  = ((const uint2*)(Ee8 + (size_t)i2 * 400))[lane];
            uint2 cc = ((const uint2*)(Ep8 + (size_t)i1 * 400))[lane];
            v2f s01 = __builtin_amdgcn_cvt_pk_f32_fp8((int)a.x, false);
            v2f s23 = __builtin_amdgcn_cvt_pk_f32_fp8((int)a.x, true);
            v2f s45 = __builtin_amdgcn_cvt_pk_f32_fp8((int)a.y, false);
            v2f s67 = __builtin_amdgcn_cvt_pk_f32_fp8((int)a.y, true);
            v2f e01 = __builtin_amdgcn_cvt_pk_f32_fp8((int)b.x, false);
            v2f e23 = __builtin_amdgcn_cvt_pk_f32_fp8((int)b.x, true);
            v2f e45 = __builtin_amdgcn_cvt_pk_f32_fp8((int)b.y, false);
            v2f e67 = __builtin_amdgcn_cvt_pk_f32_fp8((int)b.y, true);
            v2f p01 = __builtin_amdgcn_cvt_pk_f32_fp8((int)cc.x, false);
            v2f p23 = __builtin_amdgcn_cvt_pk_f32_fp8((int)cc.x, true);
            v2f p45 = __builtin_amdgcn_cvt_pk_f32_fp8((int)cc.y, false);
            v2f p67 = __builtin_amdgcn_cvt_pk_f32_fp8((int)cc.y, true);
            zs[0] = s01.x + e01.x + p01.x + qv[0];
            zs[1] = s01.y + e01.y + p01.y + qv[1];
            zs[2] = s23.x + e23.x + p23.x + qv[2];
            zs[3] = s23.y + e23.y + p23.y + qv[3];
            zs[4] = s45.x + e45.x + p45.x + qv[4];
            zs[5] = s45.y + e45.y + p45.y + qv[5];
            zs[6] = s67.x + e67.x + p67.x + qv[6];
            zs[7] = s67.y + e67.y + p67.y + qv[7];
#else
            const __hip_bfloat16* Es = (const __hip_bfloat16*)Esv;
            const __hip_bfloat16* Ee = (const __hip_bfloat16*)Eev;
            const __hip_bfloat16* Ep = (const __hip_bfloat16*)Epv;
            uint4 a  = *((const uint4*)(Es + (size_t)i0 * 400) + lane);
            uint4 b  = *((const uint4*)(Ee + (size_t)i2 * 400) + lane);
            uint4 cc = *((const uint4*)(Ep + (size_t)i1 * 400) + lane);
            zs[0] = lo2f(a.x)+lo2f(b.x)+lo2f(cc.x)+qv[0];
            zs[1] = hi2f(a.x)+hi2f(b.x)+hi2f(cc.x)+qv[1];
            zs[2] = lo2f(a.y)+lo2f(b.y)+lo2f(cc.y)+qv[2];
            zs[3] = hi2f(a.y)+hi2f(b.y)+hi2f(cc.y)+qv[3];
            zs[4] = lo2f(a.z)+lo2f(b.z)+lo2f(cc.z)+qv[4];
            zs[5] = hi2f(a.z)+hi2f(b.z)+hi2f(cc.z)+qv[5];
            zs[6] = lo2f(a.w)+lo2f(b.w)+lo2f(cc.w)+qv[6];
            zs[7] = hi2f(a.w)+hi2f(b.w)+hi2f(cc.w)+qv[7];
#endif
#pragma unroll
            for (int jj = 0; jj < 8; jj++) sum = fmaf(fast_tanh(zs[jj]), wv[jj], sum);
        }
#pragma unroll
        for (int off = 32; off; off >>= 1) sum += __shfl_xor(sum, off);
        if (lane == 0) ctx[(size_t)bt * 100 + l] = sum;
    }
}

// ---------- softmax over T: one wave per (b,l) ----------
__global__ __launch_bounds__(256) void softmax_w(
    const float* __restrict__ ctx, float* __restrict__ attn)
{
    int wid = blockIdx.x * 4 + (threadIdx.x >> 6);   // 0..1599
    int lane = threadIdx.x & 63;
    int b = wid / 100, l = wid - b * 100;
    size_t base = (size_t)b * 128 * 100 + l;
    float v0 = ctx[base + (size_t)lane * 100];
    float v1 = ctx[base + (size_t)(lane + 64) * 100];
    float m = fmaxf(v0, v1);
#pragma unroll
    for (int off = 32; off; off >>= 1) m = fmaxf(m, __shfl_xor(m, off));
    float e0 = __expf(v0 - m), e1 = __expf(v1 - m);
    float s = e0 + e1;
#pragma unroll
    for (int off = 32; off; off >>= 1) s += __shfl_xor(s, off);
    float rs = 1.f / s;
    attn[base + (size_t)lane * 100] = e0 * rs;
    attn[base + (size_t)(lane + 64) * 100] = e1 * rs;
}

// ---------- stage C: weighted re-gather of raw embeddings (bf16) ----------
__global__ __launch_bounds__(128) void stage_c(
    const float* __restrict__ x, const float* __restrict__ attn,
    const unsigned short* __restrict__ ENb, const unsigned short* __restrict__ EPb,
    float* __restrict__ cv)
{
    __shared__ float at[100];
    __shared__ int idx[300];
    int bt = blockIdx.x, tid = threadIdx.x;
    if (tid < 100) at[tid] = attn[(size_t)bt * 100 + tid];
    const float* xr = x + (size_t)bt * 400 + 100;
    for (int i = tid; i < 300; i += 128) idx[i] = (int)xr[i];
    __syncthreads();
    int d = tid;
    if (d < 100) {
        float as = 0.f, ae = 0.f, ap = 0.f, sa = 0.f;
#pragma unroll 4
        for (int l = 0; l < 100; l++) {
            float a = at[l]; sa += a;
            as = fmaf(a, lo2f(ENb[(size_t)idx[3 * l] * 100 + d]), as);
            ae = fmaf(a, lo2f(ENb[(size_t)idx[3 * l + 2] * 100 + d]), ae);
            ap = fmaf(a, lo2f(EPb[(size_t)idx[3 * l + 1] * 100 + d]), ap);
        }
        float* o = cv + (size_t)bt * 400;
        o[d] = as; o[100 + d] = ae; o[200 + d] = ap;
        o[300 + d] = x[(size_t)bt * 400 + d] * sa;
    }
}

// ---------- X = rnn_in @ Wih.T + biases ----------
__global__ __launch_bounds__(512) void gemm_x(
    const float* __restrict__ x, const float* __restrict__ cv,
    const float* __restrict__ WihT, const float* __restrict__ bih,
    const float* __restrict__ bhh, float* __restrict__ X)
{
    __shared__ float ins[8][500];
    int r0 = blockIdx.x * 8, tid = threadIdx.x;
    for (int i = tid; i < 4000; i += 512) {
        int r = i / 500, k = i - r * 500;
        ins[r][k] = (k < 100) ? x[(size_t)(r0 + r) * 400 + k]
                              : cv[(size_t)(r0 + r) * 400 + (k - 100)];
    }
    __syncthreads();
    int g = tid;
    float acc[8];
#pragma unroll
    for (int r = 0; r < 8; r++) acc[r] = 0.f;
    for (int k4 = 0; k4 < 125; k4++) {
        int k = k4 * 4;
        float w0 = WihT[(size_t)k * 512 + g];
        float w1 = WihT[(size_t)(k + 1) * 512 + g];
        float w2 = WihT[(size_t)(k + 2) * 512 + g];
        float w3 = WihT[(size_t)(k + 3) * 512 + g];
#pragma unroll
        for (int r = 0; r < 8; r++) {
            float4 a = *(const float4*)&ins[r][k];
            acc[r] = fmaf(a.x, w0, fmaf(a.y, w1, fmaf(a.z, w2, fmaf(a.w, w3, acc[r]))));
        }
    }
    float bias = bih[g] + bhh[g];
#pragma unroll
    for (int r = 0; r < 8; r++) X[(size_t)(r0 + r) * 512 + g] = acc[r] + bias;
}

// ---------- LSTM via MFMA: 4 waves (1/SIMD), double-buffered h ----------
// Wave w owns hidden units [w*32, w*32+32): for gate n, col-tiles at
// n*128 + w*32 + {0,16}. B-frag per tile: lane(col,kg) holds
// Whh_bf[g*128 + kk*32 + kg*8 .. +8] (mapping verified since R3; only
// col bases moved). A row 0 = h; D row 0 -> lanes 0-15, reg 0.
// One barrier per step; h double-buffered so no read/write race.
// All per-step traffic is LDS-only; X staged per 16-step chunk.
__global__ __launch_bounds__(256, 1) void lstm_k(
    const float* __restrict__ X, const __hip_bfloat16* __restrict__ Whh_bf,
    float* __restrict__ hs)
{
    int b = blockIdx.x, tid = threadIdx.x;
    int wave = tid >> 6, lane = tid & 63;
    int col = lane & 15, kg = lane >> 4;

    short8 bf[4][2][4];   // [gate][half][kchunk] -> 128 VGPRs
#pragma unroll
    for (int n = 0; n < 4; n++)
#pragma unroll
        for (int h2 = 0; h2 < 2; h2++) {
            int g = n * 128 + wave * 32 + h2 * 16 + col;
#pragma unroll
            for (int kk = 0; kk < 4; kk++)
                bf[n][h2][kk] = *(const short8*)(Whh_bf + (size_t)g * 128 + kk * 32 + kg * 8);
        }

    __shared__ __hip_bfloat16 hbuf[2][128];
    __shared__ float Xs[16 * 512];    // 32 KB: current 16-step X chunk
    __shared__ float hsb_s[16][128];  // 8 KB
    float c0 = 0.f, c1 = 0.f;
    if (tid < 128) hbuf[0][tid] = __float2bfloat16(0.f);
    const float* xb = X + (size_t)b * 128 * 512;
    float* hb = hs + (size_t)b * 128 * 128;
    int j0 = wave * 32 + col, j1 = j0 + 16;
    int p = 0;
    __syncthreads();

    for (int tc = 0; tc < 8; tc++) {
        // ---- refill Xs (coalesced, once per chunk) ----
        {
            const float* src = xb + (size_t)tc * 8192;
#pragma unroll
            for (int k = 0; k < 32; k++) Xs[k * 256 + tid] = src[k * 256 + tid];
        }
        __syncthreads();   // drains refill loads (and prior chunk's flush)

#pragma unroll 1
        for (int ts = 0; ts < 16; ts++) {
            short8 af[4];
            short8 zz = {};
#pragma unroll
            for (int kk = 0; kk < 4; kk++) {
                af[kk] = zz;
                if (col == 0) af[kk] = *(const short8*)(&hbuf[p][0] + kk * 32 + kg * 8);
            }
            f32x4 acc[4][2];
#pragma unroll
            for (int n = 0; n < 4; n++) {
                acc[n][0] = (f32x4){0.f, 0.f, 0.f, 0.f};
                acc[n][1] = (f32x4){0.f, 0.f, 0.f, 0.f};
            }
#pragma unroll
            for (int kk = 0; kk < 4; kk++)
#pragma unroll
                for (int n = 0; n < 4; n++) {
                    acc[n][0] = __builtin_amdgcn_mfma_f32_16x16x32_bf16(af[kk], bf[n][0][kk], acc[n][0], 0, 0, 0);
                    acc[n][1] = __builtin_amdgcn_mfma_f32_16x16x32_bf16(af[kk], bf[n][1][kk], acc[n][1], 0, 0, 0);
                }

            if (lane < 16) {
                const float* xs = &Xs[ts * 512];
                float pi0 = acc[0][0][0] + xs[j0];
                float pf0 = acc[1][0][0] + xs[128 + j0];
                float pg0 = acc[2][0][0] + xs[256 + j0];
                float po0 = acc[3][0][0] + xs[384 + j0];
                float pi1 = acc[0][1][0] + xs[j1];
                float pf1 = acc[1][1][0] + xs[128 + j1];
                float pg1 = acc[2][1][0] + xs[256 + j1];
                float po1 = acc[3][1][0] + xs[384 + j1];
                c0 = sigm(pf0) * c0 + sigm(pi0) * fast_tanh(pg0);
                float h0 = sigm(po0) * fast_tanh(c0);
                c1 = sigm(pf1) * c1 + sigm(pi1) * fast_tanh(pg1);
                float h1 = sigm(po1) * fast_tanh(c1);
                hbuf[p ^ 1][j0] = __float2bfloat16(h0);
                hbuf[p ^ 1][j1] = __float2bfloat16(h1);
                hsb_s[ts][j0] = h0;
                hsb_s[ts][j1] = h1;
            }
            __syncthreads();   // LDS-only outstanding -> near-free
            p ^= 1;
        }

        // ---- flush hsb_s -> global (drained at next refill's barrier) ----
        {
            float* dst = hb + (size_t)tc * 2048;
#pragma unroll
            for (int k = 0; k < 8; k++) {
                int i = k * 256 + tid;
                dst[i] = hsb_s[i >> 7][i & 127];
            }
        }
    }
}

__global__ __launch_bounds__(64) void fc_k(
    const float* __restrict__ hs, const float* __restrict__ Wfc,
    const float* __restrict__ bfc, float* __restrict__ out)
{
    int r0 = blockIdx.x * 4, o = threadIdx.x;
    if (o >= 50) return;
    float acc[4] = {0.f, 0.f, 0.f, 0.f};
    for (int j = 0; j < 128; j++) {
        float wv = Wfc[j * 50 + o];
#pragma unroll
        for (int r = 0; r < 4; r++)
            acc[r] = fmaf(hs[(size_t)(r0 + r) * 128 + j], wv, acc[r]);
    }
    float bb = bfc[o];
#pragma unroll
    for (int r = 0; r < 4; r++) out[(size_t)(r0 + r) * 50 + o] = sigm(acc[r] + bb);
}

extern "C" void kernel_launch(void* const* d_in, const int* in_sizes, int n_in,
                              void* d_out, int out_size, void* d_ws, size_t ws_size,
                              hipStream_t stream) {
    const float* x   = (const float*)d_in[0];
    const float* EN  = (const float*)d_in[1];
    const float* EP  = (const float*)d_in[2];
    const float* Wt  = (const float*)d_in[3];
    const float* bt  = (const float*)d_in[4];
    const float* Wa  = (const float*)d_in[5];
    // d_in[6] = b_a: uniform shift along the softmax axis -> cancels, unused.
    const float* Wih = (const float*)d_in[7];
    const float* Whh = (const float*)d_in[8];
    const float* bih = (const float*)d_in[9];
    const float* bhh = (const float*)d_in[10];
    const float* Wfc = (const float*)d_in[11];
    const float* bfc = (const float*)d_in[12];
    float* out = (float*)d_out;

    char* ws = (char*)d_ws;
    size_t off = 0;
    auto alloc = [&](size_t bytes) -> char* {
        char* p = ws + off;
        off = (off + bytes + 255) & ~(size_t)255;
        return p;
    };
    // Sized for bf16 worst case; fp8 mode uses half of each.
    void* Es  = (void*)alloc((size_t)VOCAB_ * 400 * 2);
    void* Ee  = (void*)alloc((size_t)VOCAB_ * 400 * 2);
    void* Epb = (void*)alloc((size_t)VOCAB_ * 400 * 2);
    __hip_bfloat16* ENb = (__hip_bfloat16*)alloc((size_t)VOCAB_ * 100 * 2);
    __hip_bfloat16* EPb = (__hip_bfloat16*)alloc((size_t)VOCAB_ * 100 * 2);
    float* q    = (float*)alloc((size_t)BT_ * 400 * 4);
    float* ctx  = (float*)alloc((size_t)BT_ * 100 * 4);
    float* attn = (float*)alloc((size_t)BT_ * 100 * 4);
    float* cv   = (float*)alloc((size_t)BT_ * 400 * 4);
    float* X    = (float*)alloc((size_t)BT_ * 512 * 4);
    float* hsb  = (float*)alloc((size_t)BT_ * 128 * 4);
    float* WihT = (float*)alloc((size_t)500 * 512 * 4);
    __hip_bfloat16* Whh_bf = (__hip_bfloat16*)alloc((size_t)512 * 128 * 2);

    setup_k<<<64 + 3 * EGRID + 256, 256, 0, stream>>>(
        x, EN, EP, Wt, bt, Wih, Whh,
        q, Es, Ee, Epb, ENb, EPb, WihT, Whh_bf);

    stage_a<<<BT_, 256, 0, stream>>>(x, Es, Ee, Epb, q, Wa, ctx);
    softmax_w<<<400, 256, 0, stream>>>(ctx, attn);
    stage_c<<<BT_, 128, 0, stream>>>(x, attn, (const unsigned short*)ENb,
                                     (const unsigned short*)EPb, cv);
    gemm_x<<<BT_ / 8, 512, 0, stream>>>(x, cv, WihT, bih, bhh, X);
    lstm_k<<<B_, 256, 0, stream>>>(X, Whh_bf, hsb);
    fc_k<<<BT_ / 4, 64, 0, stream>>>(hsb, Wfc, bfc, out);
}

// Round 7
// 266.667 us; speedup vs baseline: 1.3236x; 1.1659x over previous
//
#include <hip/hip_runtime.h>
#include <hip/hip_bf16.h>
#include <stdint.h>

#define B_     16
#define T_     128
#define L_     100
#define IN_    100
#define EMB_   100
#define FEAT_  400
#define HID_   128
#define OUT_   50
#define RNNIN_ 500
#define VOCAB_ 10002
#define BT_    2048

// fp8 e4m3 HW-convert availability (gfx950). Fallback = bf16 tables.
#if defined(__has_builtin)
#if __has_builtin(__builtin_amdgcn_cvt_pk_f32_fp8) && __has_builtin(__builtin_amdgcn_cvt_pk_fp8_f32)
#define HAVE_FP8 1
#endif
#endif
#ifndef HAVE_FP8
#define HAVE_FP8 0
#endif

typedef __attribute__((ext_vector_type(8))) short short8;
typedef __attribute__((ext_vector_type(4))) float f32x4;
typedef __attribute__((ext_vector_type(2))) float v2f;

__device__ __forceinline__ float lo2f(unsigned int u) {
    union { unsigned int i; float f; } v; v.i = u << 16; return v.f;
}
__device__ __forceinline__ float hi2f(unsigned int u) {
    union { unsigned int i; float f; } v; v.i = u & 0xffff0000u; return v.f;
}
__device__ __forceinline__ float fast_tanh(float x) {
    x = fminf(15.f, fmaxf(-15.f, x));
    float e = __expf(2.f * x);
    return (e - 1.f) * __builtin_amdgcn_rcpf(e + 1.f);
}
__device__ __forceinline__ float sigm(float x) {
    x = fminf(30.f, fmaxf(-30.f, x));
    float e = __expf(-x);
    return __builtin_amdgcn_rcpf(1.f + e);
}

// ---------- C[r][j] = sum_i A[r][i] * Wt[wrow+i][j], 32 rows/block ----------
// mode: 0 = f32 out, 1 = bf16 out, 2 = fp8 e4m3 out (if available)
__device__ __forceinline__ void table_gemm_body(
    const float* __restrict__ A, int lda, int rows,
    const float* __restrict__ Wt, int wrow,
    const float* __restrict__ bias, void* __restrict__ outp, int mode, int r0)
{
    __shared__ float As[32][100];
    int tid = threadIdx.x;
    for (int i = tid; i < 3200; i += 256) {
        int r = i / 100, c = i - r * 100;
        int gr = r0 + r;
        As[r][c] = (gr < rows) ? A[(size_t)gr * lda + c] : 0.f;
    }
    __syncthreads();
    int jj = tid & 63, rr = tid >> 6;
    float acc[8][7];
#pragma unroll
    for (int k = 0; k < 8; k++)
#pragma unroll
        for (int m = 0; m < 7; m++) acc[k][m] = 0.f;
    for (int i = 0; i < 100; i++) {
        float w[7];
#pragma unroll
        for (int m = 0; m < 7; m++) {
            int j = jj + (m << 6);
            w[m] = (j < 400) ? Wt[(size_t)(wrow + i) * 400 + j] : 0.f;
        }
#pragma unroll
        for (int k = 0; k < 8; k++) {
            float a = As[rr * 8 + k][i];
#pragma unroll
            for (int m = 0; m < 7; m++) acc[k][m] = fmaf(a, w[m], acc[k][m]);
        }
    }
#pragma unroll
    for (int k = 0; k < 8; k++) {
        int gr = r0 + rr * 8 + k;
        if (gr >= rows) continue;
#pragma unroll
        for (int m = 0; m < 7; m++) {
            int j = jj + (m << 6);
            if (j >= 400) continue;
            float v = acc[k][m];
            if (bias) v += bias[j];
#if HAVE_FP8
            if (mode == 2) {
                unsigned u = (unsigned)__builtin_amdgcn_cvt_pk_fp8_f32(v, v, 0, false);
                ((unsigned char*)outp)[(size_t)gr * 400 + j] = (unsigned char)(u & 0xff);
            } else
#endif
            if (mode == 1) ((__hip_bfloat16*)outp)[(size_t)gr * 400 + j] = __float2bfloat16(v);
            else           ((float*)outp)[(size_t)gr * 400 + j] = v;
        }
    }
}

#if HAVE_FP8
#define TBL_MODE 2
#else
#define TBL_MODE 1
#endif

#define EGRID 313   // ceil(VOCAB_/32)

// ---------- merged setup: table_gemm_q | table_gemm3 | prep casts ----------
__global__ __launch_bounds__(256) void setup_k(
    const float* __restrict__ x, const float* __restrict__ EN,
    const float* __restrict__ EP, const float* __restrict__ Wt,
    const float* __restrict__ bt, const float* __restrict__ Wih,
    const float* __restrict__ Whh,
    float* __restrict__ q,
    void* __restrict__ Es, void* __restrict__ Ee, void* __restrict__ Epb,
    __hip_bfloat16* __restrict__ ENb, __hip_bfloat16* __restrict__ EPb,
    float* __restrict__ WihT, __hip_bfloat16* __restrict__ Whh_bf)
{
    int blk = blockIdx.x;
    if (blk < 64) {
        table_gemm_body(x, 400, BT_, Wt, 300, bt, (void*)q, 0, blk * 32);
    } else if (blk < 64 + 3 * EGRID) {
        int t = blk - 64;
        int which = t / EGRID, r0 = (t - which * EGRID) * 32;
        const float* A = (which == 2) ? EP : EN;
        void* o = (which == 0) ? Es : ((which == 1) ? Ee : Epb);
        table_gemm_body(A, 100, VOCAB_, Wt, which * 100, nullptr, o, TBL_MODE, r0);
    } else {
        int t0 = (blk - (64 + 3 * EGRID)) * 256 + threadIdx.x;
        const int stride = 256 * 256;
        int n1 = VOCAB_ * 100;
        for (int i = t0; i < n1; i += stride) ENb[i] = __float2bfloat16(EN[i]);
        for (int i = t0; i < n1; i += stride) EPb[i] = __float2bfloat16(EP[i]);
        for (int i = t0; i < 512 * 500; i += stride) {
            int r = i / 500, c = i - r * 500;
            WihT[(size_t)c * 512 + r] = Wih[i];
        }
        for (int i = t0; i < 512 * 128; i += stride) Whh_bf[i] = __float2bfloat16(Whh[i]);
    }
}

// ---------- stage A: ctx[bt][l] = sum_j tanh(Es+Ee+Ep+q)*Wa ----------
__global__ __launch_bounds__(256) void stage_a(
    const float* __restrict__ x,
    const void* __restrict__ Esv, const void* __restrict__ Eev,
    const void* __restrict__ Epv,
    const float* __restrict__ q, const float* __restrict__ Wa,
    float* __restrict__ ctx)
{
    __shared__ int idx_s[300];
    int bt = blockIdx.x, tid = threadIdx.x;
    const float* xr = x + (size_t)bt * 400 + 100;
    for (int i = tid; i < 300; i += 256) idx_s[i] = (int)xr[i];
    int lane = tid & 63, wave = tid >> 6;
    bool act = lane < 50;
    int j0 = lane * 8;
    float qv[8], wv[8];
    if (act) {
        float4 qa = *(const float4*)(q + (size_t)bt * 400 + j0);
        float4 qb = *(const float4*)(q + (size_t)bt * 400 + j0 + 4);
        float4 wa = *(const float4*)(Wa + j0);
        float4 wb = *(const float4*)(Wa + j0 + 4);
        qv[0]=qa.x; qv[1]=qa.y; qv[2]=qa.z; qv[3]=qa.w;
        qv[4]=qb.x; qv[5]=qb.y; qv[6]=qb.z; qv[7]=qb.w;
        wv[0]=wa.x; wv[1]=wa.y; wv[2]=wa.z; wv[3]=wa.w;
        wv[4]=wb.x; wv[5]=wb.y; wv[6]=wb.z; wv[7]=wb.w;
    } else {
#pragma unroll
        for (int jj = 0; jj < 8; jj++) { qv[jj] = 0.f; wv[jj] = 0.f; }
    }
    __syncthreads();
    for (int l = wave; l < 100; l += 4) {
        int i0 = idx_s[3 * l], i1 = idx_s[3 * l + 1], i2 = idx_s[3 * l + 2];
        float sum = 0.f;
        if (act) {
            float zs[8];
#if HAVE_FP8
            const unsigned char* Es8 = (const unsigned char*)Esv;
            const unsigned char* Ee8 = (const unsigned char*)Eev;
            const unsigned char* Ep8 = (const unsigned char*)Epv;
            uint2 a  = ((const uint2*)(Es8 + (size_t)i0 * 400))[lane];
            uint2 b  = ((const uint2*)(Ee8 + (size_t)i2 * 400))[lane];
            uint2 cc = ((const uint2*)(Ep8 + (size_t)i1 * 400))[lane];
            v2f s01 = __builtin_amdgcn_cvt_pk_f32_fp8((int)a.x, false);
            v2f s23 = __builtin_amdgcn_cvt_pk_f32_fp8((int)a.x, true);
            v2f s45 = __builtin_amdgcn_cvt_pk_f32_fp8((int)a.y, false);
            v2f s67 = __builtin_amdgcn_cvt_pk_f32_fp8((int)a.y, true);
            v2f e01 = __builtin_amdgcn_cvt_pk_f32_fp8((int)b.x, false);
            v2f e23 = __builtin_amdgcn_cvt_pk_f32_fp8((int)b.x, true);
            v2f e45 = __builtin_amdgcn_cvt_pk_f32_fp8((int)b.y, false);
            v2f e67 = __builtin_amdgcn_cvt_pk_f32_fp8((int)b.y, true);
            v2f p01 = __builtin_amdgcn_cvt_pk_f32_fp8((int)cc.x, false);
            v2f p23 = __builtin_amdgcn_cvt_pk_f32_fp8((int)cc.x, true);
            v2f p45 = __builtin_amdgcn_cvt_pk_f32_fp8((int)cc.y, false);
            v2f p67 = __builtin_amdgcn_cvt_pk_f32_fp8((int)cc.y, true);
            zs[0] = s01.x + e01.x + p01.x + qv[0];
            zs[1] = s01.y + e01.y + p01.y + qv[1];
            zs[2] = s23.x + e23.x + p23.x + qv[2];
            zs[3] = s23.y + e23.y + p23.y + qv[3];
            zs[4] = s45.x + e45.x + p45.x + qv[4];
            zs[5] = s45.y + e45.y + p45.y + qv[5];
            zs[6] = s67.x + e67.x + p67.x + qv[6];
            zs[7] = s67.y + e67.y + p67.y + qv[7];
#else
            const __hip_bfloat16* Es = (const __hip_bfloat16*)Esv;
            const __hip_bfloat16* Ee = (const __hip_bfloat16*)Eev;
            const __hip_bfloat16* Ep = (const __hip_bfloat16*)Epv;
            uint4 a  = *((const uint4*)(Es + (size_t)i0 * 400) + lane);
            uint4 b  = *((const uint4*)(Ee + (size_t)i2 * 400) + lane);
            uint4 cc = *((const uint4*)(Ep + (size_t)i1 * 400) + lane);
            zs[0] = lo2f(a.x)+lo2f(b.x)+lo2f(cc.x)+qv[0];
            zs[1] = hi2f(a.x)+hi2f(b.x)+hi2f(cc.x)+qv[1];
            zs[2] = lo2f(a.y)+lo2f(b.y)+lo2f(cc.y)+qv[2];
            zs[3] = hi2f(a.y)+hi2f(b.y)+hi2f(cc.y)+qv[3];
            zs[4] = lo2f(a.z)+lo2f(b.z)+lo2f(cc.z)+qv[4];
            zs[5] = hi2f(a.z)+hi2f(b.z)+hi2f(cc.z)+qv[5];
            zs[6] = lo2f(a.w)+lo2f(b.w)+lo2f(cc.w)+qv[6];
            zs[7] = hi2f(a.w)+hi2f(b.w)+hi2f(cc.w)+qv[7];
#endif
#pragma unroll
            for (int jj = 0; jj < 8; jj++) sum = fmaf(fast_tanh(zs[jj]), wv[jj], sum);
        }
#pragma unroll
        for (int off = 32; off; off >>= 1) sum += __shfl_xor(sum, off);
        if (lane == 0) ctx[(size_t)bt * 100 + l] = sum;
    }
}

// ---------- softmax over T: one wave per (b,l) ----------
__global__ __launch_bounds__(256) void softmax_w(
    const float* __restrict__ ctx, float* __restrict__ attn)
{
    int wid = blockIdx.x * 4 + (threadIdx.x >> 6);   // 0..1599
    int lane = threadIdx.x & 63;
    int b = wid / 100, l = wid - b * 100;
    size_t base = (size_t)b * 128 * 100 + l;
    float v0 = ctx[base + (size_t)lane * 100];
    float v1 = ctx[base + (size_t)(lane + 64) * 100];
    float m = fmaxf(v0, v1);
#pragma unroll
    for (int off = 32; off; off >>= 1) m = fmaxf(m, __shfl_xor(m, off));
    float e0 = __expf(v0 - m), e1 = __expf(v1 - m);
    float s = e0 + e1;
#pragma unroll
    for (int off = 32; off; off >>= 1) s += __shfl_xor(s, off);
    float rs = 1.f / s;
    attn[base + (size_t)lane * 100] = e0 * rs;
    attn[base + (size_t)(lane + 64) * 100] = e1 * rs;
}

// ---------- stage C: weighted re-gather of raw embeddings (bf16) ----------
__global__ __launch_bounds__(128) void stage_c(
    const float* __restrict__ x, const float* __restrict__ attn,
    const unsigned short* __restrict__ ENb, const unsigned short* __restrict__ EPb,
    float* __restrict__ cv)
{
    __shared__ float at[100];
    __shared__ int idx[300];
    int bt = blockIdx.x, tid = threadIdx.x;
    if (tid < 100) at[tid] = attn[(size_t)bt * 100 + tid];
    const float* xr = x + (size_t)bt * 400 + 100;
    for (int i = tid; i < 300; i += 128) idx[i] = (int)xr[i];
    __syncthreads();
    int d = tid;
    if (d < 100) {
        float as = 0.f, ae = 0.f, ap = 0.f, sa = 0.f;
#pragma unroll 4
        for (int l = 0; l < 100; l++) {
            float a = at[l]; sa += a;
            as = fmaf(a, lo2f(ENb[(size_t)idx[3 * l] * 100 + d]), as);
            ae = fmaf(a, lo2f(ENb[(size_t)idx[3 * l + 2] * 100 + d]), ae);
            ap = fmaf(a, lo2f(EPb[(size_t)idx[3 * l + 1] * 100 + d]), ap);
        }
        float* o = cv + (size_t)bt * 400;
        o[d] = as; o[100 + d] = ae; o[200 + d] = ap;
        o[300 + d] = x[(size_t)bt * 400 + d] * sa;
    }
}

// ---------- X = rnn_in @ Wih.T + biases ----------
__global__ __launch_bounds__(512) void gemm_x(
    const float* __restrict__ x, const float* __restrict__ cv,
    const float* __restrict__ WihT, const float* __restrict__ bih,
    const float* __restrict__ bhh, float* __restrict__ X)
{
    __shared__ float ins[8][500];
    int r0 = blockIdx.x * 8, tid = threadIdx.x;
    for (int i = tid; i < 4000; i += 512) {
        int r = i / 500, k = i - r * 500;
        ins[r][k] = (k < 100) ? x[(size_t)(r0 + r) * 400 + k]
                              : cv[(size_t)(r0 + r) * 400 + (k - 100)];
    }
    __syncthreads();
    int g = tid;
    float acc[8];
#pragma unroll
    for (int r = 0; r < 8; r++) acc[r] = 0.f;
    for (int k4 = 0; k4 < 125; k4++) {
        int k = k4 * 4;
        float w0 = WihT[(size_t)k * 512 + g];
        float w1 = WihT[(size_t)(k + 1) * 512 + g];
        float w2 = WihT[(size_t)(k + 2) * 512 + g];
        float w3 = WihT[(size_t)(k + 3) * 512 + g];
#pragma unroll
        for (int r = 0; r < 8; r++) {
            float4 a = *(const float4*)&ins[r][k];
            acc[r] = fmaf(a.x, w0, fmaf(a.y, w1, fmaf(a.z, w2, fmaf(a.w, w3, acc[r]))));
        }
    }
    float bias = bih[g] + bhh[g];
#pragma unroll
    for (int r = 0; r < 8; r++) X[(size_t)(r0 + r) * 512 + g] = acc[r] + bias;
}

// ---------- LSTM via MFMA (R4 structure, proven 75 us) + double-buffered h ----------
// 8 waves; wave w owns hidden units j in [w*16, w*16+16).
// Tile n (n=0:i 1:f 2:g 3:o) covers gate-cols [n*128 + w*16, +16).
// B-frag: lane(col,kg) holds Whh_bf[g*128 + kk*32 + kg*8 .. +8], g = n*128+w*16+col.
// A-frag row 0 = h; D row 0 -> lanes 0-15 acc[n][0].
// One barrier per step; all per-step traffic is LDS-only (X staged per
// 16-step chunk, h flushed per chunk) so the vmcnt(0) drain at each
// __syncthreads is already satisfied.
__global__ __launch_bounds__(512, 1) void lstm_k(
    const float* __restrict__ X, const __hip_bfloat16* __restrict__ Whh_bf,
    float* __restrict__ hs)
{
    int b = blockIdx.x, tid = threadIdx.x;
    int wave = tid >> 6, lane = tid & 63;
    int col = lane & 15, kg = lane >> 4;

    short8 bf[4][4];
#pragma unroll
    for (int n = 0; n < 4; n++) {
        int g = n * 128 + wave * 16 + col;
#pragma unroll
        for (int kk = 0; kk < 4; kk++)
            bf[n][kk] = *(const short8*)(Whh_bf + (size_t)g * 128 + kk * 32 + kg * 8);
    }

    __shared__ __hip_bfloat16 hbuf[2][128];
    __shared__ float Xs[16][512];     // 32 KB: current 16-step X chunk
    __shared__ float hsb_s[16][128];  // 8 KB: h outputs for this chunk
    float c = 0.f;
    if (tid < 128) hbuf[0][tid] = __float2bfloat16(0.f);
    const float* xb = X + (size_t)b * 128 * 512;
    float* hb = hs + (size_t)b * 128 * 128;
    int j = wave * 16 + col;
    int p = 0;

    __syncthreads();

    for (int tc = 0; tc < 8; tc++) {
        // ---- refill Xs with steps tc*16 .. tc*16+15 (coalesced, once/chunk) ----
        {
            const float* src = xb + (size_t)tc * 16 * 512 + tid;
#pragma unroll
            for (int k = 0; k < 16; k++) Xs[k][tid] = src[k * 512];
        }
        __syncthreads();   // drains refill loads (and prior chunk's flush stores)

#pragma unroll 1
        for (int ts = 0; ts < 16; ts++) {
            short8 af[4];
            short8 zz = {};
#pragma unroll
            for (int kk = 0; kk < 4; kk++) {
                af[kk] = zz;
                if (col == 0) af[kk] = *(const short8*)(&hbuf[p][0] + kk * 32 + kg * 8);
            }
            f32x4 acc[4];
#pragma unroll
            for (int n = 0; n < 4; n++) acc[n] = (f32x4){0.f, 0.f, 0.f, 0.f};
#pragma unroll
            for (int kk = 0; kk < 4; kk++)
#pragma unroll
                for (int n = 0; n < 4; n++)
                    acc[n] = __builtin_amdgcn_mfma_f32_16x16x32_bf16(af[kk], bf[n][kk], acc[n], 0, 0, 0);

            if (lane < 16) {
                float pi = acc[0][0] + Xs[ts][j];
                float pf = acc[1][0] + Xs[ts][128 + j];
                float pg = acc[2][0] + Xs[ts][256 + j];
                float po = acc[3][0] + Xs[ts][384 + j];
                c = sigm(pf) * c + sigm(pi) * fast_tanh(pg);
                float hn = sigm(po) * fast_tanh(c);
                hbuf[p ^ 1][j] = __float2bfloat16(hn);
                hsb_s[ts][j] = hn;
            }
            __syncthreads();   // LDS-only outstanding -> near-free
            p ^= 1;
        }

        // ---- flush hsb_s -> global (fire-and-forget; drained at next refill) ----
        {
            float* dst = hb + (size_t)tc * 16 * 128;
#pragma unroll
            for (int k = 0; k < 4; k++) {
                int i = k * 512 + tid;
                dst[i] = hsb_s[i >> 7][i & 127];
            }
        }
    }
}

__global__ __launch_bounds__(64) void fc_k(
    const float* __restrict__ hs, const float* __restrict__ Wfc,
    const float* __restrict__ bfc, float* __restrict__ out)
{
    int r0 = blockIdx.x * 4, o = threadIdx.x;
    if (o >= 50) return;
    float acc[4] = {0.f, 0.f, 0.f, 0.f};
    for (int j = 0; j < 128; j++) {
        float wv = Wfc[j * 50 + o];
#pragma unroll
        for (int r = 0; r < 4; r++)
            acc[r] = fmaf(hs[(size_t)(r0 + r) * 128 + j], wv, acc[r]);
    }
    float bb = bfc[o];
#pragma unroll
    for (int r = 0; r < 4; r++) out[(size_t)(r0 + r) * 50 + o] = sigm(acc[r] + bb);
}

extern "C" void kernel_launch(void* const* d_in, const int* in_sizes, int n_in,
                              void* d_out, int out_size, void* d_ws, size_t ws_size,
                              hipStream_t stream) {
    const float* x   = (const float*)d_in[0];
    const float* EN  = (const float*)d_in[1];
    const float* EP  = (const float*)d_in[2];
    const float* Wt  = (const float*)d_in[3];
    const float* bt  = (const float*)d_in[4];
    const float* Wa  = (const float*)d_in[5];
    // d_in[6] = b_a: uniform shift along the softmax axis -> cancels, unused.
    const float* Wih = (const float*)d_in[7];
    const float* Whh = (const float*)d_in[8];
    const float* bih = (const float*)d_in[9];
    const float* bhh = (const float*)d_in[10];
    const float* Wfc = (const float*)d_in[11];
    const float* bfc = (const float*)d_in[12];
    float* out = (float*)d_out;

    char* ws = (char*)d_ws;
    size_t off = 0;
    auto alloc = [&](size_t bytes) -> char* {
        char* p = ws + off;
        off = (off + bytes + 255) & ~(size_t)255;
        return p;
    };
    // Sized for bf16 worst case; fp8 mode uses half of each.
    void* Es  = (void*)alloc((size_t)VOCAB_ * 400 * 2);
    void* Ee  = (void*)alloc((size_t)VOCAB_ * 400 * 2);
    void* Epb = (void*)alloc((size_t)VOCAB_ * 400 * 2);
    __hip_bfloat16* ENb = (__hip_bfloat16*)alloc((size_t)VOCAB_ * 100 * 2);
    __hip_bfloat16* EPb = (__hip_bfloat16*)alloc((size_t)VOCAB_ * 100 * 2);
    float* q    = (float*)alloc((size_t)BT_ * 400 * 4);
    float* ctx  = (float*)alloc((size_t)BT_ * 100 * 4);
    float* attn = (float*)alloc((size_t)BT_ * 100 * 4);
    float* cv   = (float*)alloc((size_t)BT_ * 400 * 4);
    float* X    = (float*)alloc((size_t)BT_ * 512 * 4);
    float* hsb  = (float*)alloc((size_t)BT_ * 128 * 4);
    float* WihT = (float*)alloc((size_t)500 * 512 * 4);
    __hip_bfloat16* Whh_bf = (__hip_bfloat16*)alloc((size_t)512 * 128 * 2);

    setup_k<<<64 + 3 * EGRID + 256, 256, 0, stream>>>(
        x, EN, EP, Wt, bt, Wih, Whh,
        q, Es, Ee, Epb, ENb, EPb, WihT, Whh_bf);

    stage_a<<<BT_, 256, 0, stream>>>(x, Es, Ee, Epb, q, Wa, ctx);
    softmax_w<<<400, 256, 0, stream>>>(ctx, attn);
    stage_c<<<BT_, 128, 0, stream>>>(x, attn, (const unsigned short*)ENb,
                                     (const unsigned short*)EPb, cv);
    gemm_x<<<BT_ / 8, 512, 0, stream>>>(x, cv, WihT, bih, bhh, X);
    lstm_k<<<B_, 512, 0, stream>>>(X, Whh_bf, hsb);
    fc_k<<<BT_ / 4, 64, 0, stream>>>(hsb, Wfc, bfc, out);
}